// Round 16
// baseline (769.111 us; speedup 1.0000x reference)
//
#include <hip/hip_runtime.h>
#include <hip/hip_bf16.h>

typedef unsigned short u16;
typedef __attribute__((ext_vector_type(8))) short short8;
typedef __attribute__((ext_vector_type(4))) float f32x4;

#define EPSV 1e-5f
#define ENC_NINF 0x007FFFFFu

__device__ __forceinline__ float bf2f(u16 u) {
    union { unsigned int i; float f; } v; v.i = ((unsigned int)u) << 16; return v.f;
}
__device__ __forceinline__ u16 f2bf(float f) {
    union { float f; unsigned int i; } v; v.f = f;
    unsigned int x = v.i;
    return (u16)((x + 0x7FFFu + ((x >> 16) & 1u)) >> 16);   // RNE
}
__device__ __forceinline__ unsigned int encbf(u16 u) {
    unsigned int f = ((unsigned int)u) << 16;
    return (f & 0x80000000u) ? ~f : (f | 0x80000000u);
}
__device__ __forceinline__ float dec(unsigned int u) {
    union { float f; unsigned int uu; } v;
    v.uu = (u & 0x80000000u) ? (u & 0x7FFFFFFFu) : ~u;
    return v.f;
}

// async 16B global -> LDS (per-lane source ok; LDS dest = uniform base + lane*16)
__device__ __forceinline__ void async16(const u16* g, u16* l) {
    __builtin_amdgcn_global_load_lds((const __attribute__((address_space(1))) void*)g,
                                     (__attribute__((address_space(3))) void*)l,
                                     16, 0, 0);
}

__global__ __launch_bounds__(256) void k_fillf(float* __restrict__ o, int n, float val)
{
    int i = blockIdx.x * 256 + threadIdx.x;
    if (i < n) o[i] = val;
}

__global__ __launch_bounds__(256) void k_initu(unsigned int* __restrict__ o, int n)
{
    int i = blockIdx.x * 256 + threadIdx.x;
    if (i < n) o[i] = ENC_NINF;
}

// ---- adaptive repack: float tensors -> bf16 blob; choice -> clean int32 ----
struct Ptrs { const void* p[17]; int off[18]; int chN; };

__global__ __launch_bounds__(256) void k_repack(Ptrs P, const void* __restrict__ chSrc,
                                                int* __restrict__ chi, u16* __restrict__ rp)
{
    const unsigned int* probe = (const unsigned int*)P.p[9];   // w3, |x| << 2
    int cnt = 0;
#pragma unroll
    for (int i = 0; i < 64; ++i) {
        unsigned int lo = probe[i] & 0xFFFFu;
        if (((lo >> 7) & 0xFFu) >= 0x80u) ++cnt;
    }
    const bool is_f32 = (cnt > 8);

    const unsigned int* cp = (const unsigned int*)chSrc;
    int z = 0; unsigned int mx = 0;
    for (int i = 0; i < 1024; ++i) {
        unsigned int w = cp[i];
        z += (w == 0u);
        mx = (w > mx) ? w : mx;
    }
    const int chMode = (mx >= 64u) ? 2 : ((z > 300) ? 1 : 0);  // 2=f32, 1=i64, 0=i32

    const int stride = gridDim.x * 256;
    const int gid0 = blockIdx.x * 256 + threadIdx.x;

    const int totalF = P.off[17];
    for (int g = gid0; g < totalF; g += stride) {
        int t = 0;
        while (g >= P.off[t + 1]) ++t;
        int off = g - P.off[t];
        u16 v;
        if (is_f32) v = f2bf(((const float*)P.p[t])[off]);
        else        v = ((const u16*)P.p[t])[off];
        rp[g] = v;
    }
    for (int i = gid0; i < P.chN; i += stride) {
        int v;
        if (chMode == 1)      v = (int)((const long long*)chSrc)[i];
        else if (chMode == 2) v = (int)((const float*)chSrc)[i];
        else                  v = ((const int*)chSrc)[i];
        chi[i] = v & 63;
    }
}

// ---- counting sort per batch: points ordered by cluster ----
__global__ __launch_bounds__(256) void k_sort(const int* __restrict__ chi,
                                              int* __restrict__ schoice,
                                              int* __restrict__ perm)
{
    __shared__ int hist[64];
    __shared__ int base[64];
    const int b = blockIdx.x, tid = threadIdx.x;
    if (tid < 64) hist[tid] = 0;
    __syncthreads();
    const int o = b << 13;
    for (int i = tid; i < 8192; i += 256) atomicAdd(&hist[chi[o + i]], 1);
    __syncthreads();
    if (tid == 0) {
        int s = 0;
        for (int k = 0; k < 64; ++k) { base[k] = s; s += hist[k]; }
    }
    __syncthreads();
    for (int i = tid; i < 8192; i += 256) {
        int k = chi[o + i];
        int pos = atomicAdd(&base[k], 1);
        schoice[o + pos] = k;
        perm[o + pos] = o + i;
    }
}

// ---- G1 (NT=2): feat = (relu(bn1(xyz.w1^T+b1))) . w2^T + b2, seg-max fused ----
// One block computes 128 rows x all 256 cols; h computed ONCE.
__global__ __launch_bounds__(256, 2) void g1_feat(
    const u16* __restrict__ xyz, const u16* __restrict__ w1, const u16* __restrict__ b1,
    const u16* __restrict__ g1v, const u16* __restrict__ bb1,
    const u16* __restrict__ m1, const u16* __restrict__ v1,
    const u16* __restrict__ w2, const u16* __restrict__ b2,
    const int* __restrict__ schoice, const int* __restrict__ perm,
    u16* __restrict__ feat, unsigned int* __restrict__ fg_u)
{
    __shared__ __align__(16) u16 Bs[256 * 128];      // 64 KB: both w2 halves
    __shared__ unsigned int lred[8 * 256];           // 8 KB (nk <= 8 fast path)
    __shared__ float4 pw[128];
    __shared__ float xs[128], ys[128], zs[128];
    __shared__ int chs[128];
    const int tid = threadIdx.x, lane = tid & 63, wave = tid >> 6;
    const int wm = (wave & 1) << 6, wn = (wave >> 1) << 6;
    const int m0 = blockIdx.x << 7;
    if (tid < 128) {
        float s = bf2f(g1v[tid]) * rsqrtf(bf2f(v1[tid]) + EPSV);
        float4 w;
        w.x = bf2f(w1[tid * 3 + 0]) * s;
        w.y = bf2f(w1[tid * 3 + 1]) * s;
        w.z = bf2f(w1[tid * 3 + 2]) * s;
        w.w = (bf2f(b1[tid]) - bf2f(m1[tid])) * s + bf2f(bb1[tid]);
        pw[tid] = w;
        const u16* p = xyz + (size_t)perm[m0 + tid] * 3;
        xs[tid] = bf2f(p[0]); ys[tid] = bf2f(p[1]); zs[tid] = bf2f(p[2]);
        chs[tid] = schoice[m0 + tid];
    }
    const int q = lane >> 4, mr = lane & 15;
    f32x4 acc[2][4][4] = {};
    // stage both w2 N-halves (256 rows x 128 K) in one shot, 16-chunk swizzle
#pragma unroll
    for (int i = 0; i < 16; ++i) {
        int id = (i << 8) + tid, row = id >> 4, cc = id & 15;
        async16(w2 + (size_t)row * 128 + ((cc ^ (row & 15)) << 3), &Bs[id << 3]);
    }
    __syncthreads();
    const int kmin = chs[0], nk = chs[127] - kmin + 1;
    const bool useL = (nk <= 8);
    if (useL) for (int i = tid; i < (nk << 8); i += 256) lred[i] = ENC_NINF;
#pragma unroll
    for (int kk = 0; kk < 4; ++kk) {
        const int lc = kk * 4 + q;
        float4 wv[8];
#pragma unroll
        for (int j = 0; j < 8; ++j) wv[j] = pw[kk * 32 + q * 8 + j];
        short8 af[4];
#pragma unroll
        for (int mi = 0; mi < 4; ++mi) {
            int row = wm + mi * 16 + mr;
            float x = xs[row], y = ys[row], z = zs[row];
#pragma unroll
            for (int j = 0; j < 8; ++j) {
                float val = fmaf(x, wv[j].x, fmaf(y, wv[j].y, fmaf(z, wv[j].z, wv[j].w)));
                af[mi][j] = (short)f2bf(fmaxf(val, 0.0f));
            }
        }
#pragma unroll
        for (int h = 0; h < 2; ++h) {
            short8 bfr[4];
#pragma unroll
            for (int ni = 0; ni < 4; ++ni) {
                int r = (h << 7) + wn + ni * 16 + mr;
                bfr[ni] = *(const short8*)&Bs[r * 128 + ((lc ^ (r & 15)) << 3)];
            }
#pragma unroll
            for (int mi = 0; mi < 4; ++mi)
#pragma unroll
                for (int ni = 0; ni < 4; ++ni)
                    acc[h][mi][ni] = __builtin_amdgcn_mfma_f32_16x16x32_bf16(af[mi], bfr[ni], acc[h][mi][ni], 0, 0, 0);
        }
    }
    __syncthreads();    // lred init complete before epilogue atomics
    const int colb = lane & 15;
    const int bl = m0 >> 13;
    unsigned int* db = fg_u + (size_t)(bl << 6) * 256;
#pragma unroll
    for (int h = 0; h < 2; ++h)
#pragma unroll
        for (int ni = 0; ni < 4; ++ni) {
            int n = (h << 7) + wn + (ni << 4) + colb;    // 0..255
            float bv = bf2f(b2[n]);
#pragma unroll
            for (int mi = 0; mi < 4; ++mi) {
                int curk = -1; unsigned int run = 0;
#pragma unroll
                for (int r = 0; r < 4; ++r) {
                    int rr = wm + (mi << 4) + (q << 2) + r;
                    u16 vb = f2bf(acc[h][mi][ni][r] + bv);
                    feat[(size_t)(m0 + rr) * 256 + n] = vb;
                    unsigned int e = encbf(vb);
                    int k = chs[rr];
                    if (k != curk) {
                        if (curk >= 0) {
                            if (useL) atomicMax(&lred[((curk - kmin) << 8) + n], run);
                            else      atomicMax(&db[curk * 256 + n], run);
                        }
                        curk = k; run = e;
                    } else run = run > e ? run : e;
                }
                if (useL) atomicMax(&lred[((curk - kmin) << 8) + n], run);
                else      atomicMax(&db[curk * 256 + n], run);
            }
        }
    if (useL) {
        __syncthreads();
        for (int i = tid; i < (nk << 8); i += 256) {
            unsigned int v = lred[i];
            if (v != ENC_NINF) atomicMax(&db[(kmin + (i >> 8)) * 256 + (i & 255)], v);
        }
    }
}

// ---- G4: out = h2 . w4^T + b4, BK=64, seg-max fused epilogue (sorted) ----
__global__ __launch_bounds__(256, 4) void g4_out(
    const u16* __restrict__ A, const u16* __restrict__ Bt,
    const u16* __restrict__ bias, const int* __restrict__ schoice,
    unsigned int* __restrict__ out_u, const int K, const int N)
{
    __shared__ __align__(16) u16 smem[2 * 128 * 64];
    __shared__ int chs[128];
    u16* As = smem;
    u16* Bs = smem + 128 * 64;
    const int tid = threadIdx.x, lane = tid & 63, wave = tid >> 6;
    const int wm = (wave & 1) << 6, wn = (wave >> 1) << 6;
    const int m0 = blockIdx.x << 7, n0 = blockIdx.y << 7;
    const int c = tid & 7, rb = tid >> 3;
    if (tid < 128) chs[tid] = schoice[m0 + tid];
    f32x4 acc[4][4] = {};
    for (int k0 = 0; k0 < K; k0 += 64) {
        __syncthreads();
#pragma unroll
        for (int i = 0; i < 4; ++i) {
            int id = (i << 8) + tid, row = id >> 3, cc = id & 7;
            async16(Bt + (n0 + row) * K + k0 + ((cc ^ (row & 7)) << 3), &Bs[id << 3]);
        }
#pragma unroll
        for (int i = 0; i < 4; ++i) {
            int r = rb + (i << 5);
            async16(A + (size_t)(m0 + r) * K + k0 + ((c ^ (r & 7)) << 3),
                    &As[(((i << 8) + tid) << 3)]);
        }
        __syncthreads();
        const int q = lane >> 4, mr = lane & 15;
#pragma unroll
        for (int kk = 0; kk < 2; ++kk) {
            short8 af[4], bfr[4];
            const int lc = kk * 4 + q;
#pragma unroll
            for (int mi = 0; mi < 4; ++mi) {
                int r = wm + mi * 16 + mr;
                af[mi] = *(const short8*)&As[r * 64 + ((lc ^ (r & 7)) << 3)];
            }
#pragma unroll
            for (int ni = 0; ni < 4; ++ni) {
                int r = wn + ni * 16 + mr;
                bfr[ni] = *(const short8*)&Bs[r * 64 + ((lc ^ (r & 7)) << 3)];
            }
#pragma unroll
            for (int mi = 0; mi < 4; ++mi)
#pragma unroll
                for (int ni = 0; ni < 4; ++ni)
                    acc[mi][ni] = __builtin_amdgcn_mfma_f32_16x16x32_bf16(af[mi], bfr[ni], acc[mi][ni], 0, 0, 0);
        }
    }
    __syncthreads();
    unsigned int* lred = (unsigned int*)smem;
    const int kmin = chs[0], nk = chs[127] - kmin + 1;
    for (int i = tid; i < (nk << 7); i += 256) lred[i] = ENC_NINF;
    __syncthreads();
    const int q = lane >> 4, colb = lane & 15;
#pragma unroll
    for (int ni = 0; ni < 4; ++ni) {
        int nc = wn + (ni << 4) + colb;
        float bv = bf2f(bias[n0 + nc]);
#pragma unroll
        for (int mi = 0; mi < 4; ++mi) {
            int curk = -1; unsigned int run = 0;
#pragma unroll
            for (int r = 0; r < 4; ++r) {
                int rr = wm + (mi << 4) + (q << 2) + r;
                unsigned int e = encbf(f2bf(acc[mi][ni][r] + bv));
                int k = chs[rr];
                if (k != curk) {
                    if (curk >= 0) atomicMax(&lred[((curk - kmin) << 7) + nc], run);
                    curk = k; run = e;
                } else run = run > e ? run : e;
            }
            atomicMax(&lred[((curk - kmin) << 7) + nc], run);
        }
    }
    __syncthreads();
    const int bl = m0 >> 13;
    unsigned int* db = out_u + (size_t)(bl << 6) * N;
    for (int i = tid; i < (nk << 7); i += 256) {
        unsigned int v = lred[i];
        if (v != ENC_NINF) atomicMax(&db[(kmin + (i >> 7)) * N + n0 + (i & 127)], v);
    }
}

__global__ __launch_bounds__(256) void k_dec_bf(const unsigned int* __restrict__ u,
                                                u16* __restrict__ o, int n)
{
    int i = blockIdx.x * 256 + threadIdx.x;
    if (i < n) o[i] = f2bf(dec(u[i]));
}
__global__ __launch_bounds__(256) void k_dec_f32(const unsigned int* __restrict__ u,
                                                 float* __restrict__ o, int n)
{
    int i = blockIdx.x * 256 + threadIdx.x;
    if (i < n) o[i] = dec(u[i]);
}

// ---- G3: h2 = relu(bn2([fg_pts|feat] . w3^T + b3)), NT=2, BK=64 (sorted rows) ----
__global__ __launch_bounds__(256, 3) void g3_h2(
    const int* __restrict__ schoice, const u16* __restrict__ feat,
    const u16* __restrict__ fg, const u16* __restrict__ w3, const u16* __restrict__ b3,
    const u16* __restrict__ g2, const u16* __restrict__ bb2,
    const u16* __restrict__ m2, const u16* __restrict__ v2,
    u16* __restrict__ h2)
{
    __shared__ __align__(16) u16 As[128 * 64];
    __shared__ __align__(16) u16 Bs[2 * 128 * 64];
    const int tid = threadIdx.x, lane = tid & 63, wave = tid >> 6;
    const int wm = (wave & 1) << 6, wn = (wave >> 1) << 6;
    const int m0 = blockIdx.x << 7, n0 = blockIdx.y << 8;   // 256-wide N group
    const int c = tid & 7, rb = tid >> 3;
    const u16* fgrow[4]; const u16* ftrow[4];
#pragma unroll
    for (int i = 0; i < 4; ++i) {
        int pt = m0 + rb + (i << 5);
        int b = pt >> 13;
        fgrow[i] = fg + (((b << 6) + schoice[pt]) << 8);
        ftrow[i] = feat + ((size_t)pt << 8);
    }
    f32x4 acc[2][4][4] = {};
    for (int k0 = 0; k0 < 512; k0 += 64) {
        __syncthreads();
#pragma unroll
        for (int nt = 0; nt < 2; ++nt)
#pragma unroll
            for (int i = 0; i < 4; ++i) {
                int id = (i << 8) + tid, row = id >> 3, cc = id & 7;
                async16(w3 + (size_t)(n0 + nt * 128 + row) * 512 + k0 + ((cc ^ (row & 7)) << 3),
                        &Bs[nt * 8192 + (id << 3)]);
            }
#pragma unroll
        for (int i = 0; i < 4; ++i) {
            int r = rb + (i << 5);
            int col = k0 + ((c ^ (r & 7)) << 3);
            const u16* src = (col < 256) ? (fgrow[i] + col) : (ftrow[i] + (col - 256));
            async16(src, &As[(((i << 8) + tid) << 3)]);
        }
        __syncthreads();
        const int q = lane >> 4, mr = lane & 15;
#pragma unroll
        for (int kk = 0; kk < 2; ++kk) {
            short8 af[4];
            const int lc = kk * 4 + q;
#pragma unroll
            for (int mi = 0; mi < 4; ++mi) {
                int r = wm + mi * 16 + mr;
                af[mi] = *(const short8*)&As[r * 64 + ((lc ^ (r & 7)) << 3)];
            }
#pragma unroll
            for (int nt = 0; nt < 2; ++nt) {
                short8 bfr[4];
#pragma unroll
                for (int ni = 0; ni < 4; ++ni) {
                    int r = wn + ni * 16 + mr;
                    bfr[ni] = *(const short8*)&Bs[nt * 8192 + r * 64 + ((lc ^ (r & 7)) << 3)];
                }
#pragma unroll
                for (int mi = 0; mi < 4; ++mi)
#pragma unroll
                    for (int ni = 0; ni < 4; ++ni)
                        acc[nt][mi][ni] = __builtin_amdgcn_mfma_f32_16x16x32_bf16(af[mi], bfr[ni], acc[nt][mi][ni], 0, 0, 0);
            }
        }
    }
    const int q = lane >> 4, colb = lane & 15;
#pragma unroll
    for (int nt = 0; nt < 2; ++nt)
#pragma unroll
        for (int ni = 0; ni < 4; ++ni) {
            int n = n0 + nt * 128 + wn + (ni << 4) + colb;
            float s = bf2f(g2[n]) * rsqrtf(bf2f(v2[n]) + EPSV);
            float t = (bf2f(b3[n]) - bf2f(m2[n])) * s + bf2f(bb2[n]);
#pragma unroll
            for (int mi = 0; mi < 4; ++mi)
#pragma unroll
                for (int r = 0; r < 4; ++r) {
                    int m = m0 + wm + (mi << 4) + (q << 2) + r;
                    h2[(size_t)m * 512 + n] = f2bf(fmaxf(fmaf(acc[nt][mi][ni][r], s, t), 0.0f));
                }
        }
}

extern "C" void kernel_launch(void* const* d_in, const int* in_sizes, int n_in,
                              void* d_out, int out_size, void* d_ws, size_t ws_size,
                              hipStream_t stream)
{
    float* out = (float*)d_out;
    if (n_in != 18) {
        k_fillf<<<dim3((out_size + 255) / 256), 256, 0, stream>>>(out, out_size, 1000.0f);
        return;
    }

    const int map[17] = {0, 2, 3, 4, 5, 6, 7, 8, 9, 10, 11, 12, 13, 14, 15, 16, 17};
    Ptrs P;
    P.off[0] = 0;
    for (int i = 0; i < 17; ++i) {
        P.p[i] = d_in[map[i]];
        P.off[i + 1] = P.off[i] + in_sizes[map[i]];
    }
    P.chN = in_sizes[1];

    char* ws = (char*)d_ws;
    int* chi = (int*)ws;
    const size_t chiB = ((size_t)P.chN * 4 + 255) & ~255ull;
    int* schoice = (int*)(ws + chiB);
    int* perm    = (int*)(ws + 2 * chiB);
    u16* rp = (u16*)(ws + 3 * chiB);
    const size_t rpB = ((size_t)P.off[17] * 2 + 255) & ~255ull;
    const size_t RPB = 3 * chiB + rpB;

    k_repack<<<dim3(1024), 256, 0, stream>>>(P, d_in[1], chi, rp);
    k_sort<<<dim3(P.chN >> 13), 256, 0, stream>>>(chi, schoice, perm);

    const u16* xyz  = rp + P.off[0];
    const u16* w1   = rp + P.off[1];
    const u16* b1   = rp + P.off[2];
    const u16* bn1g = rp + P.off[3];
    const u16* bn1b = rp + P.off[4];
    const u16* bn1m = rp + P.off[5];
    const u16* bn1v = rp + P.off[6];
    const u16* w2   = rp + P.off[7];
    const u16* b2   = rp + P.off[8];
    const u16* w3   = rp + P.off[9];
    const u16* b3   = rp + P.off[10];
    const u16* bn2g = rp + P.off[11];
    const u16* bn2b = rp + P.off[12];
    const u16* bn2m = rp + P.off[13];
    const u16* bn2v = rp + P.off[14];
    const u16* w4   = rp + P.off[15];
    const u16* b4   = rp + P.off[16];

    // fixed region: fg_u (32*64*256 u32) + out_u (32*64*384 u32) = 5,242,880 B
    unsigned int* fg_u_all  = (unsigned int*)(ws + RPB);
    unsigned int* out_u_all = fg_u_all + 32 * 64 * 256;
    const size_t UB = 5242880ull;
    const int nU = 32 * 64 * 640;

    // per-batch: feat 4,194,304 + h2 8,388,608 + fg 32,768 = 12,615,680
    const size_t PB = 12615680ull;
    int sb = 32;
    while (sb > 1 && RPB + UB + (size_t)sb * PB > ws_size) sb >>= 1;
    if (RPB + UB + PB > ws_size) {
        k_fillf<<<dim3((out_size + 255) / 256), 256, 0, stream>>>(out, out_size, 3000.0f);
        return;
    }
    const int ns = 32 / sb;

    char* wsb = ws + RPB + UB;
    const size_t featB = (size_t)sb * 8192 * 256 * 2;
    const size_t h2B   = (size_t)sb * 8192 * 512 * 2;
    u16* feat = (u16*)(wsb);
    u16* h2s  = (u16*)(wsb + featB);
    u16* fg   = (u16*)(wsb + featB + h2B);

    k_initu<<<dim3((nU + 255) / 256), 256, 0, stream>>>(fg_u_all, nU);

    const int mblk = sb << 6;        // 128-row M-tiles per slice
    const int nfg = sb * 64 * 256;
    const int nou = sb * 64 * 384;
    for (int s = 0; s < ns; ++s) {
        const int b0 = s * sb;
        const int pt0 = b0 << 13;
        const int* sch_sl = schoice + pt0;
        const int* perm_sl = perm + pt0;
        unsigned int* fg_u  = fg_u_all + (size_t)b0 * 64 * 256;
        unsigned int* out_u = out_u_all + (size_t)b0 * 64 * 384;
        g1_feat<<<dim3(mblk), 256, 0, stream>>>(xyz, w1, b1, bn1g, bn1b, bn1m, bn1v,
                                                w2, b2, sch_sl, perm_sl, feat, fg_u);
        k_dec_bf<<<dim3((nfg + 255) / 256), 256, 0, stream>>>(fg_u, fg, nfg);
        g3_h2<<<dim3(mblk, 2), 256, 0, stream>>>(sch_sl, feat, fg, w3, b3,
                                                 bn2g, bn2b, bn2m, bn2v, h2s);
        g4_out<<<dim3(mblk, 3), 256, 0, stream>>>(h2s, w4, b4, sch_sl, out_u, 512, 384);
        k_dec_f32<<<dim3((nou + 255) / 256), 256, 0, stream>>>(out_u,
                                                               out + ((size_t)b0 << 6) * 384, nou);
    }
}

// Round 17
// 520.663 us; speedup vs baseline: 1.4772x; 1.4772x over previous
//
#include <hip/hip_runtime.h>
#include <hip/hip_bf16.h>

typedef unsigned short u16;
typedef __attribute__((ext_vector_type(8))) short short8;
typedef __attribute__((ext_vector_type(4))) float f32x4;

#define EPSV 1e-5f
#define ENC_NINF 0x007FFFFFu

__device__ __forceinline__ float bf2f(u16 u) {
    union { unsigned int i; float f; } v; v.i = ((unsigned int)u) << 16; return v.f;
}
__device__ __forceinline__ u16 f2bf(float f) {
    union { float f; unsigned int i; } v; v.f = f;
    unsigned int x = v.i;
    return (u16)((x + 0x7FFFu + ((x >> 16) & 1u)) >> 16);   // RNE
}
__device__ __forceinline__ unsigned int encbf(u16 u) {
    unsigned int f = ((unsigned int)u) << 16;
    return (f & 0x80000000u) ? ~f : (f | 0x80000000u);
}
__device__ __forceinline__ float dec(unsigned int u) {
    union { float f; unsigned int uu; } v;
    v.uu = (u & 0x80000000u) ? (u & 0x7FFFFFFFu) : ~u;
    return v.f;
}

// async 16B global -> LDS (per-lane source ok; LDS dest = uniform base + lane*16)
__device__ __forceinline__ void async16(const u16* g, u16* l) {
    __builtin_amdgcn_global_load_lds((const __attribute__((address_space(1))) void*)g,
                                     (__attribute__((address_space(3))) void*)l,
                                     16, 0, 0);
}

__global__ __launch_bounds__(256) void k_fillf(float* __restrict__ o, int n, float val)
{
    int i = blockIdx.x * 256 + threadIdx.x;
    if (i < n) o[i] = val;
}

__global__ __launch_bounds__(256) void k_initu(unsigned int* __restrict__ o, int n)
{
    int i = blockIdx.x * 256 + threadIdx.x;
    if (i < n) o[i] = ENC_NINF;
}

// ---- adaptive repack: float tensors -> bf16 blob; choice -> clean int32 ----
struct Ptrs { const void* p[17]; int off[18]; int chN; };

__global__ __launch_bounds__(256) void k_repack(Ptrs P, const void* __restrict__ chSrc,
                                                int* __restrict__ chi, u16* __restrict__ rp)
{
    const unsigned int* probe = (const unsigned int*)P.p[9];   // w3, |x| << 2
    int cnt = 0;
#pragma unroll
    for (int i = 0; i < 64; ++i) {
        unsigned int lo = probe[i] & 0xFFFFu;
        if (((lo >> 7) & 0xFFu) >= 0x80u) ++cnt;
    }
    const bool is_f32 = (cnt > 8);

    const unsigned int* cp = (const unsigned int*)chSrc;
    int z = 0; unsigned int mx = 0;
    for (int i = 0; i < 1024; ++i) {
        unsigned int w = cp[i];
        z += (w == 0u);
        mx = (w > mx) ? w : mx;
    }
    const int chMode = (mx >= 64u) ? 2 : ((z > 300) ? 1 : 0);  // 2=f32, 1=i64, 0=i32

    const int stride = gridDim.x * 256;
    const int gid0 = blockIdx.x * 256 + threadIdx.x;

    const int totalF = P.off[17];
    for (int g = gid0; g < totalF; g += stride) {
        int t = 0;
        while (g >= P.off[t + 1]) ++t;
        int off = g - P.off[t];
        u16 v;
        if (is_f32) v = f2bf(((const float*)P.p[t])[off]);
        else        v = ((const u16*)P.p[t])[off];
        rp[g] = v;
    }
    for (int i = gid0; i < P.chN; i += stride) {
        int v;
        if (chMode == 1)      v = (int)((const long long*)chSrc)[i];
        else if (chMode == 2) v = (int)((const float*)chSrc)[i];
        else                  v = ((const int*)chSrc)[i];
        chi[i] = v & 63;
    }
}

// ---- counting sort per batch: points ordered by cluster ----
__global__ __launch_bounds__(256) void k_sort(const int* __restrict__ chi,
                                              int* __restrict__ schoice,
                                              int* __restrict__ perm)
{
    __shared__ int hist[64];
    __shared__ int base[64];
    const int b = blockIdx.x, tid = threadIdx.x;
    if (tid < 64) hist[tid] = 0;
    __syncthreads();
    const int o = b << 13;
    for (int i = tid; i < 8192; i += 256) atomicAdd(&hist[chi[o + i]], 1);
    __syncthreads();
    if (tid == 0) {
        int s = 0;
        for (int k = 0; k < 64; ++k) { base[k] = s; s += hist[k]; }
    }
    __syncthreads();
    for (int i = tid; i < 8192; i += 256) {
        int k = chi[o + i];
        int pos = atomicAdd(&base[k], 1);
        schoice[o + pos] = k;
        perm[o + pos] = o + i;
    }
}

// ---- G1 (NT=2): feat = (relu(bn1(xyz.w1^T+b1))) . w2^T + b2, seg-max fused ----
// One block computes 128 rows x all 256 cols; h computed ONCE.
__global__ __launch_bounds__(256, 2) void g1_feat(
    const u16* __restrict__ xyz, const u16* __restrict__ w1, const u16* __restrict__ b1,
    const u16* __restrict__ g1v, const u16* __restrict__ bb1,
    const u16* __restrict__ m1, const u16* __restrict__ v1,
    const u16* __restrict__ w2, const u16* __restrict__ b2,
    const int* __restrict__ schoice, const int* __restrict__ perm,
    u16* __restrict__ feat, unsigned int* __restrict__ fg_u)
{
    __shared__ __align__(16) u16 Bs[256 * 128];      // 64 KB: both w2 halves
    __shared__ unsigned int lred[8 * 256];           // 8 KB (nk <= 8 fast path)
    __shared__ float4 pw[128];
    __shared__ float xs[128], ys[128], zs[128];
    __shared__ int chs[128];
    const int tid = threadIdx.x, lane = tid & 63, wave = tid >> 6;
    const int wm = (wave & 1) << 6, wn = (wave >> 1) << 6;
    const int m0 = blockIdx.x << 7;
    if (tid < 128) {
        float s = bf2f(g1v[tid]) * rsqrtf(bf2f(v1[tid]) + EPSV);
        float4 w;
        w.x = bf2f(w1[tid * 3 + 0]) * s;
        w.y = bf2f(w1[tid * 3 + 1]) * s;
        w.z = bf2f(w1[tid * 3 + 2]) * s;
        w.w = (bf2f(b1[tid]) - bf2f(m1[tid])) * s + bf2f(bb1[tid]);
        pw[tid] = w;
        const u16* p = xyz + (size_t)perm[m0 + tid] * 3;
        xs[tid] = bf2f(p[0]); ys[tid] = bf2f(p[1]); zs[tid] = bf2f(p[2]);
        chs[tid] = schoice[m0 + tid];
    }
    const int q = lane >> 4, mr = lane & 15;
    f32x4 acc[2][4][4] = {};
    // stage both w2 N-halves (256 rows x 128 K) in one shot, 16-chunk swizzle
#pragma unroll
    for (int i = 0; i < 16; ++i) {
        int id = (i << 8) + tid, row = id >> 4, cc = id & 15;
        async16(w2 + (size_t)row * 128 + ((cc ^ (row & 15)) << 3), &Bs[id << 3]);
    }
    __syncthreads();
    const int kmin = chs[0], nk = chs[127] - kmin + 1;
    const bool useL = (nk <= 8);
    if (useL) for (int i = tid; i < (nk << 8); i += 256) lred[i] = ENC_NINF;
#pragma unroll
    for (int kk = 0; kk < 4; ++kk) {
        const int lc = kk * 4 + q;
        float4 wv[8];
#pragma unroll
        for (int j = 0; j < 8; ++j) wv[j] = pw[kk * 32 + q * 8 + j];
        short8 af[4];
#pragma unroll
        for (int mi = 0; mi < 4; ++mi) {
            int row = wm + mi * 16 + mr;
            float x = xs[row], y = ys[row], z = zs[row];
#pragma unroll
            for (int j = 0; j < 8; ++j) {
                float val = fmaf(x, wv[j].x, fmaf(y, wv[j].y, fmaf(z, wv[j].z, wv[j].w)));
                af[mi][j] = (short)f2bf(fmaxf(val, 0.0f));
            }
        }
#pragma unroll
        for (int h = 0; h < 2; ++h) {
            short8 bfr[4];
#pragma unroll
            for (int ni = 0; ni < 4; ++ni) {
                int r = (h << 7) + wn + ni * 16 + mr;
                bfr[ni] = *(const short8*)&Bs[r * 128 + ((lc ^ (r & 15)) << 3)];
            }
#pragma unroll
            for (int mi = 0; mi < 4; ++mi)
#pragma unroll
                for (int ni = 0; ni < 4; ++ni)
                    acc[h][mi][ni] = __builtin_amdgcn_mfma_f32_16x16x32_bf16(af[mi], bfr[ni], acc[h][mi][ni], 0, 0, 0);
        }
    }
    __syncthreads();    // lred init complete before epilogue atomics
    const int colb = lane & 15;
    const int bl = m0 >> 13;
    unsigned int* db = fg_u + (size_t)(bl << 6) * 256;
#pragma unroll
    for (int h = 0; h < 2; ++h)
#pragma unroll
        for (int ni = 0; ni < 4; ++ni) {
            int n = (h << 7) + wn + (ni << 4) + colb;    // 0..255
            float bv = bf2f(b2[n]);
#pragma unroll
            for (int mi = 0; mi < 4; ++mi) {
                int curk = -1; unsigned int run = 0;
#pragma unroll
                for (int r = 0; r < 4; ++r) {
                    int rr = wm + (mi << 4) + (q << 2) + r;
                    u16 vb = f2bf(acc[h][mi][ni][r] + bv);
                    feat[(size_t)(m0 + rr) * 256 + n] = vb;
                    unsigned int e = encbf(vb);
                    int k = chs[rr];
                    if (k != curk) {
                        if (curk >= 0) {
                            if (useL) atomicMax(&lred[((curk - kmin) << 8) + n], run);
                            else      atomicMax(&db[curk * 256 + n], run);
                        }
                        curk = k; run = e;
                    } else run = run > e ? run : e;
                }
                if (useL) atomicMax(&lred[((curk - kmin) << 8) + n], run);
                else      atomicMax(&db[curk * 256 + n], run);
            }
        }
    if (useL) {
        __syncthreads();
        for (int i = tid; i < (nk << 8); i += 256) {
            unsigned int v = lred[i];
            if (v != ENC_NINF) atomicMax(&db[(kmin + (i >> 8)) * 256 + (i & 255)], v);
        }
    }
}

// ---- G4: out = h2 . w4^T + b4, BK=64, seg-max fused epilogue (r14 form) ----
__global__ __launch_bounds__(256) void g4_out(
    const u16* __restrict__ A, const u16* __restrict__ Bt,
    const u16* __restrict__ bias, const int* __restrict__ schoice,
    unsigned int* __restrict__ out_u, const int K, const int N)
{
    __shared__ __align__(16) u16 smem[2 * 128 * 64];
    __shared__ int chs[128];
    u16* As = smem;
    u16* Bs = smem + 128 * 64;
    const int tid = threadIdx.x, lane = tid & 63, wave = tid >> 6;
    const int wm = (wave & 1) << 6, wn = (wave >> 1) << 6;
    const int m0 = blockIdx.x << 7, n0 = blockIdx.y << 7;
    const int c = tid & 7, rb = tid >> 3;
    if (tid < 128) chs[tid] = schoice[m0 + tid];
    f32x4 acc[4][4] = {};
    for (int k0 = 0; k0 < K; k0 += 64) {
        __syncthreads();
#pragma unroll
        for (int i = 0; i < 4; ++i) {
            int id = (i << 8) + tid, row = id >> 3, cc = id & 7;
            async16(Bt + (n0 + row) * K + k0 + ((cc ^ (row & 7)) << 3), &Bs[id << 3]);
        }
#pragma unroll
        for (int i = 0; i < 4; ++i) {
            int r = rb + (i << 5);
            async16(A + (size_t)(m0 + r) * K + k0 + ((c ^ (r & 7)) << 3),
                    &As[(((i << 8) + tid) << 3)]);
        }
        __syncthreads();
        const int q = lane >> 4, mr = lane & 15;
#pragma unroll
        for (int kk = 0; kk < 2; ++kk) {
            short8 af[4], bfr[4];
            const int lc = kk * 4 + q;
#pragma unroll
            for (int mi = 0; mi < 4; ++mi) {
                int r = wm + mi * 16 + mr;
                af[mi] = *(const short8*)&As[r * 64 + ((lc ^ (r & 7)) << 3)];
            }
#pragma unroll
            for (int ni = 0; ni < 4; ++ni) {
                int r = wn + ni * 16 + mr;
                bfr[ni] = *(const short8*)&Bs[r * 64 + ((lc ^ (r & 7)) << 3)];
            }
#pragma unroll
            for (int mi = 0; mi < 4; ++mi)
#pragma unroll
                for (int ni = 0; ni < 4; ++ni)
                    acc[mi][ni] = __builtin_amdgcn_mfma_f32_16x16x32_bf16(af[mi], bfr[ni], acc[mi][ni], 0, 0, 0);
        }
    }
    __syncthreads();
    unsigned int* lred = (unsigned int*)smem;
    const int kmin = chs[0], nk = chs[127] - kmin + 1;
    for (int i = tid; i < (nk << 7); i += 256) lred[i] = ENC_NINF;
    __syncthreads();
    const int q = lane >> 4, colb = lane & 15;
#pragma unroll
    for (int ni = 0; ni < 4; ++ni) {
        int nc = wn + (ni << 4) + colb;
        float bv = bf2f(bias[n0 + nc]);
#pragma unroll
        for (int mi = 0; mi < 4; ++mi) {
            int curk = -1; unsigned int run = 0;
#pragma unroll
            for (int r = 0; r < 4; ++r) {
                int rr = wm + (mi << 4) + (q << 2) + r;
                unsigned int e = encbf(f2bf(acc[mi][ni][r] + bv));
                int k = chs[rr];
                if (k != curk) {
                    if (curk >= 0) atomicMax(&lred[((curk - kmin) << 7) + nc], run);
                    curk = k; run = e;
                } else run = run > e ? run : e;
            }
            atomicMax(&lred[((curk - kmin) << 7) + nc], run);
        }
    }
    __syncthreads();
    const int bl = m0 >> 13;
    unsigned int* db = out_u + (size_t)(bl << 6) * N;
    for (int i = tid; i < (nk << 7); i += 256) {
        unsigned int v = lred[i];
        if (v != ENC_NINF) atomicMax(&db[(kmin + (i >> 7)) * N + n0 + (i & 127)], v);
    }
}

__global__ __launch_bounds__(256) void k_dec_bf(const unsigned int* __restrict__ u,
                                                u16* __restrict__ o, int n)
{
    int i = blockIdx.x * 256 + threadIdx.x;
    if (i < n) o[i] = f2bf(dec(u[i]));
}
__global__ __launch_bounds__(256) void k_dec_f32(const unsigned int* __restrict__ u,
                                                 float* __restrict__ o, int n)
{
    int i = blockIdx.x * 256 + threadIdx.x;
    if (i < n) o[i] = dec(u[i]);
}

// ---- G3: h2 = relu(bn2([fg_pts|feat] . w3^T + b3)), NT=2, BK=64 (r14 form) ----
__global__ __launch_bounds__(256, 2) void g3_h2(
    const int* __restrict__ schoice, const u16* __restrict__ feat,
    const u16* __restrict__ fg, const u16* __restrict__ w3, const u16* __restrict__ b3,
    const u16* __restrict__ g2, const u16* __restrict__ bb2,
    const u16* __restrict__ m2, const u16* __restrict__ v2,
    u16* __restrict__ h2)
{
    __shared__ __align__(16) u16 As[128 * 64];
    __shared__ __align__(16) u16 Bs[2 * 128 * 64];
    const int tid = threadIdx.x, lane = tid & 63, wave = tid >> 6;
    const int wm = (wave & 1) << 6, wn = (wave >> 1) << 6;
    const int m0 = blockIdx.x << 7, n0 = blockIdx.y << 8;   // 256-wide N group
    const int c = tid & 7, rb = tid >> 3;
    const u16* fgrow[4]; const u16* ftrow[4];
#pragma unroll
    for (int i = 0; i < 4; ++i) {
        int pt = m0 + rb + (i << 5);
        int b = pt >> 13;
        fgrow[i] = fg + (((b << 6) + schoice[pt]) << 8);
        ftrow[i] = feat + ((size_t)pt << 8);
    }
    f32x4 acc[2][4][4] = {};
    for (int k0 = 0; k0 < 512; k0 += 64) {
        __syncthreads();
#pragma unroll
        for (int nt = 0; nt < 2; ++nt)
#pragma unroll
            for (int i = 0; i < 4; ++i) {
                int id = (i << 8) + tid, row = id >> 3, cc = id & 7;
                async16(w3 + (size_t)(n0 + nt * 128 + row) * 512 + k0 + ((cc ^ (row & 7)) << 3),
                        &Bs[nt * 8192 + (id << 3)]);
            }
#pragma unroll
        for (int i = 0; i < 4; ++i) {
            int r = rb + (i << 5);
            int col = k0 + ((c ^ (r & 7)) << 3);
            const u16* src = (col < 256) ? (fgrow[i] + col) : (ftrow[i] + (col - 256));
            async16(src, &As[(((i << 8) + tid) << 3)]);
        }
        __syncthreads();
        const int q = lane >> 4, mr = lane & 15;
#pragma unroll
        for (int kk = 0; kk < 2; ++kk) {
            short8 af[4];
            const int lc = kk * 4 + q;
#pragma unroll
            for (int mi = 0; mi < 4; ++mi) {
                int r = wm + mi * 16 + mr;
                af[mi] = *(const short8*)&As[r * 64 + ((lc ^ (r & 7)) << 3)];
            }
#pragma unroll
            for (int nt = 0; nt < 2; ++nt) {
                short8 bfr[4];
#pragma unroll
                for (int ni = 0; ni < 4; ++ni) {
                    int r = wn + ni * 16 + mr;
                    bfr[ni] = *(const short8*)&Bs[nt * 8192 + r * 64 + ((lc ^ (r & 7)) << 3)];
                }
#pragma unroll
                for (int mi = 0; mi < 4; ++mi)
#pragma unroll
                    for (int ni = 0; ni < 4; ++ni)
                        acc[nt][mi][ni] = __builtin_amdgcn_mfma_f32_16x16x32_bf16(af[mi], bfr[ni], acc[nt][mi][ni], 0, 0, 0);
            }
        }
    }
    const int q = lane >> 4, colb = lane & 15;
#pragma unroll
    for (int nt = 0; nt < 2; ++nt)
#pragma unroll
        for (int ni = 0; ni < 4; ++ni) {
            int n = n0 + nt * 128 + wn + (ni << 4) + colb;
            float s = bf2f(g2[n]) * rsqrtf(bf2f(v2[n]) + EPSV);
            float t = (bf2f(b3[n]) - bf2f(m2[n])) * s + bf2f(bb2[n]);
#pragma unroll
            for (int mi = 0; mi < 4; ++mi)
#pragma unroll
                for (int r = 0; r < 4; ++r) {
                    int m = m0 + wm + (mi << 4) + (q << 2) + r;
                    h2[(size_t)m * 512 + n] = f2bf(fmaxf(fmaf(acc[nt][mi][ni][r], s, t), 0.0f));
                }
        }
}

extern "C" void kernel_launch(void* const* d_in, const int* in_sizes, int n_in,
                              void* d_out, int out_size, void* d_ws, size_t ws_size,
                              hipStream_t stream)
{
    float* out = (float*)d_out;
    if (n_in != 18) {
        k_fillf<<<dim3((out_size + 255) / 256), 256, 0, stream>>>(out, out_size, 1000.0f);
        return;
    }

    const int map[17] = {0, 2, 3, 4, 5, 6, 7, 8, 9, 10, 11, 12, 13, 14, 15, 16, 17};
    Ptrs P;
    P.off[0] = 0;
    for (int i = 0; i < 17; ++i) {
        P.p[i] = d_in[map[i]];
        P.off[i + 1] = P.off[i] + in_sizes[map[i]];
    }
    P.chN = in_sizes[1];

    char* ws = (char*)d_ws;
    int* chi = (int*)ws;
    const size_t chiB = ((size_t)P.chN * 4 + 255) & ~255ull;
    int* schoice = (int*)(ws + chiB);
    int* perm    = (int*)(ws + 2 * chiB);
    u16* rp = (u16*)(ws + 3 * chiB);
    const size_t rpB = ((size_t)P.off[17] * 2 + 255) & ~255ull;
    const size_t RPB = 3 * chiB + rpB;

    k_repack<<<dim3(1024), 256, 0, stream>>>(P, d_in[1], chi, rp);
    k_sort<<<dim3(P.chN >> 13), 256, 0, stream>>>(chi, schoice, perm);

    const u16* xyz  = rp + P.off[0];
    const u16* w1   = rp + P.off[1];
    const u16* b1   = rp + P.off[2];
    const u16* bn1g = rp + P.off[3];
    const u16* bn1b = rp + P.off[4];
    const u16* bn1m = rp + P.off[5];
    const u16* bn1v = rp + P.off[6];
    const u16* w2   = rp + P.off[7];
    const u16* b2   = rp + P.off[8];
    const u16* w3   = rp + P.off[9];
    const u16* b3   = rp + P.off[10];
    const u16* bn2g = rp + P.off[11];
    const u16* bn2b = rp + P.off[12];
    const u16* bn2m = rp + P.off[13];
    const u16* bn2v = rp + P.off[14];
    const u16* w4   = rp + P.off[15];
    const u16* b4   = rp + P.off[16];

    // fixed region: fg_u (32*64*256 u32) + out_u (32*64*384 u32) = 5,242,880 B
    unsigned int* fg_u_all  = (unsigned int*)(ws + RPB);
    unsigned int* out_u_all = fg_u_all + 32 * 64 * 256;
    const size_t UB = 5242880ull;
    const int nU = 32 * 64 * 640;

    // per-batch: feat 4,194,304 + h2 8,388,608 + fg 32,768 = 12,615,680
    const size_t PB = 12615680ull;
    int sb = 32;
    while (sb > 1 && RPB + UB + (size_t)sb * PB > ws_size) sb >>= 1;
    if (RPB + UB + PB > ws_size) {
        k_fillf<<<dim3((out_size + 255) / 256), 256, 0, stream>>>(out, out_size, 3000.0f);
        return;
    }
    const int ns = 32 / sb;

    char* wsb = ws + RPB + UB;
    const size_t featB = (size_t)sb * 8192 * 256 * 2;
    const size_t h2B   = (size_t)sb * 8192 * 512 * 2;
    u16* feat = (u16*)(wsb);
    u16* h2s  = (u16*)(wsb + featB);
    u16* fg   = (u16*)(wsb + featB + h2B);

    k_initu<<<dim3((nU + 255) / 256), 256, 0, stream>>>(fg_u_all, nU);

    const int mblk = sb << 6;        // 128-row M-tiles per slice
    const int nfg = sb * 64 * 256;
    const int nou = sb * 64 * 384;
    for (int s = 0; s < ns; ++s) {
        const int b0 = s * sb;
        const int pt0 = b0 << 13;
        const int* sch_sl = schoice + pt0;
        const int* perm_sl = perm + pt0;
        unsigned int* fg_u  = fg_u_all + (size_t)b0 * 64 * 256;
        unsigned int* out_u = out_u_all + (size_t)b0 * 64 * 384;
        g1_feat<<<dim3(mblk), 256, 0, stream>>>(xyz, w1, b1, bn1g, bn1b, bn1m, bn1v,
                                                w2, b2, sch_sl, perm_sl, feat, fg_u);
        k_dec_bf<<<dim3((nfg + 255) / 256), 256, 0, stream>>>(fg_u, fg, nfg);
        g3_h2<<<dim3(mblk, 2), 256, 0, stream>>>(sch_sl, feat, fg, w3, b3,
                                                 bn2g, bn2b, bn2m, bn2v, h2s);
        g4_out<<<dim3(mblk, 3), 256, 0, stream>>>(h2s, w4, b4, sch_sl, out_u, 512, 384);
        k_dec_f32<<<dim3((nou + 255) / 256), 256, 0, stream>>>(out_u,
                                                               out + ((size_t)b0 << 6) * 384, nou);
    }
}